// Round 10
// baseline (2977.011 us; speedup 1.0000x reference)
//
#include <hip/hip_runtime.h>

#define DI __device__ __forceinline__

namespace {

constexpr int kL  = 2048;
constexpr int kB  = 4;
constexpr int kE  = 512;
constexpr int kHD = 64;
constexpr int kFF = 2048;
constexpr int kNE = 5;
constexpr int kT  = 8192;   // kL * kB tokens
constexpr int kCAP = 4;

DI float bf2f(unsigned short u) { return __uint_as_float(((unsigned)u) << 16); }
DI unsigned short f2bf(float f) {
  unsigned u = __float_as_uint(f);
  u = u + 0x7FFFu + ((u >> 16) & 1u);
  return (unsigned short)(u >> 16);
}

DI unsigned rotl(unsigned v, int d) { return (v << d) | (v >> (32 - d)); }

// JAX threefry2x32 with key = PRNGKey(42) = (0, 42), 20 rounds.
DI void threefry(unsigned& x0, unsigned& x1) {
  const unsigned K1 = 0u, K2 = 42u, K3 = 0x1BD11BDAu ^ 0u ^ 42u;
  x0 += K1; x1 += K2;
  x0 += x1; x1 = rotl(x1, 13); x1 ^= x0;
  x0 += x1; x1 = rotl(x1, 15); x1 ^= x0;
  x0 += x1; x1 = rotl(x1, 26); x1 ^= x0;
  x0 += x1; x1 = rotl(x1,  6); x1 ^= x0;
  x0 += K2; x1 += K3 + 1u;
  x0 += x1; x1 = rotl(x1, 17); x1 ^= x0;
  x0 += x1; x1 = rotl(x1, 29); x1 ^= x0;
  x0 += x1; x1 = rotl(x1, 16); x1 ^= x0;
  x0 += x1; x1 = rotl(x1, 24); x1 ^= x0;
  x0 += K3; x1 += K1 + 2u;
  x0 += x1; x1 = rotl(x1, 13); x1 ^= x0;
  x0 += x1; x1 = rotl(x1, 15); x1 ^= x0;
  x0 += x1; x1 = rotl(x1, 26); x1 ^= x0;
  x0 += x1; x1 = rotl(x1,  6); x1 ^= x0;
  x0 += K1; x1 += K2 + 3u;
  x0 += x1; x1 = rotl(x1, 17); x1 ^= x0;
  x0 += x1; x1 = rotl(x1, 29); x1 ^= x0;
  x0 += x1; x1 = rotl(x1, 16); x1 ^= x0;
  x0 += x1; x1 = rotl(x1, 24); x1 ^= x0;
  x0 += K2; x1 += K3 + 4u;
  x0 += x1; x1 = rotl(x1, 13); x1 ^= x0;
  x0 += x1; x1 = rotl(x1, 15); x1 ^= x0;
  x0 += x1; x1 = rotl(x1, 26); x1 ^= x0;
  x0 += x1; x1 = rotl(x1,  6); x1 ^= x0;
  x0 += K3; x1 += K1 + 5u;
}

// ---------------- LayerNorm (one row per block, 256 threads, E=512) -----------
__global__ __launch_bounds__(256) void ln_kernel(
    const float* __restrict__ x, const float* __restrict__ w,
    const float* __restrict__ b, float* __restrict__ out) {
  int row = blockIdx.x;
  const float* xr = x + (size_t)row * kE;
  int t = threadIdx.x;
  float2 v = *(const float2*)(xr + t * 2);
  __shared__ float red[4];
  float s = v.x + v.y;
  #pragma unroll
  for (int m = 32; m; m >>= 1) s += __shfl_xor(s, m);
  if ((t & 63) == 0) red[t >> 6] = s;
  __syncthreads();
  float mu = (red[0] + red[1] + red[2] + red[3]) * (1.0f / kE);
  float dx = v.x - mu, dy = v.y - mu;
  float q = dx * dx + dy * dy;
  #pragma unroll
  for (int m = 32; m; m >>= 1) q += __shfl_xor(q, m);
  __syncthreads();
  if ((t & 63) == 0) red[t >> 6] = q;
  __syncthreads();
  float var = (red[0] + red[1] + red[2] + red[3]) * (1.0f / kE);
  float inv = 1.0f / sqrtf(var + 1e-5f);
  float2 o;
  o.x = dx * inv * w[t * 2]     + b[t * 2];
  o.y = dy * inv * w[t * 2 + 1] + b[t * 2 + 1];
  *(float2*)(out + (size_t)row * kE + t * 2) = o;
}

// ---------------- Generic 128x128 f32 GEMM (XCD-swizzled, pipelined) ---------
// BT=1: C = A[MxK] * B[NxK]^T   (B row-major [N][K])
// BT=0: C = A[MxK] * B[KxN]     (B row-major [K][N])
// MOE: per-expert via blockIdx.z, M = cnt[e], C rows offset by base[e],
//      B offset e*bExpStride. GATHER: A rows = tokOfRow[globalRow].
// Grid (x*y) must be a multiple of 8 for the bijective XCD swizzle.
template <int BT, int MOE, int GATHER, int BIAS, int RES, int RELU, int BF16A, int BF16OUT>
__global__ __launch_bounds__(256) void gemm_kernel(
    const void* __restrict__ Ap, const float* __restrict__ Bp,
    const float* __restrict__ biasp, const float* __restrict__ Rp,
    void* __restrict__ Cp, int M, int N, int K,
    const int* __restrict__ gatherp, const int* __restrict__ cntp,
    const int* __restrict__ basep, int bExpStride) {
  __shared__ float As[16][128];
  __shared__ float Bs[16][128];

  // XCD-aware swizzle: XCD c gets contiguous work range -> A row-panels
  // loaded once per XCD, B stays L2-resident per XCD.
  int nwg = gridDim.x * gridDim.y;
  int bid = blockIdx.y * gridDim.x + blockIdx.x;
  int swz = (bid & 7) * (nwg >> 3) + (bid >> 3);
  int wx = swz % gridDim.x, wy = swz / gridDim.x;

  int rowOff = 0;
  const float* Bmat = Bp;
  if (MOE) {
    int e = blockIdx.z;
    M = cntp[e];
    rowOff = basep[e];
    Bmat = Bp + (size_t)e * bExpStride;
    if (wy * 128 >= M) return;
  }
  const int m0 = wy * 128;
  const int n0 = wx * 128;
  const int t = threadIdx.x;
  const int tx = t & 15, ty = t >> 4;

  const int ar = t >> 2;         // 0..63
  const int ak = (t & 3) * 4;    // k offset 0/4/8/12
  size_t arow0, arow1;
  {
    int r0 = m0 + ar, r1 = m0 + ar + 64;
    if (MOE) {
      int mm = M - 1;
      r0 = r0 < mm ? r0 : mm;
      r1 = r1 < mm ? r1 : mm;
      if (GATHER) { r0 = gatherp[rowOff + r0]; r1 = gatherp[rowOff + r1]; }
      else        { r0 += rowOff; r1 += rowOff; }
    }
    arow0 = (size_t)r0 * K + ak;
    arow1 = (size_t)r1 * K + ak;
  }
  int b_r, b_o;
  if (BT) { b_r = t >> 2; b_o = (t & 3) * 4; }   // row n in tile, k offset
  else    { b_r = t >> 4; b_o = (t & 15) * 4; }  // row k in tile, n offset

  float acc[8][8];
  #pragma unroll
  for (int i = 0; i < 8; ++i)
    #pragma unroll
    for (int j = 0; j < 8; ++j) acc[i][j] = 0.0f;

  float a0[4], a1[4];
  float4 w0, w1v;
  auto load_tile = [&](int k0) {
    if (BF16A) {
      const unsigned short* Ab = (const unsigned short*)Ap;
      ushort4 u0 = *(const ushort4*)(Ab + arow0 + k0);
      ushort4 u1 = *(const ushort4*)(Ab + arow1 + k0);
      a0[0]=bf2f(u0.x); a0[1]=bf2f(u0.y); a0[2]=bf2f(u0.z); a0[3]=bf2f(u0.w);
      a1[0]=bf2f(u1.x); a1[1]=bf2f(u1.y); a1[2]=bf2f(u1.z); a1[3]=bf2f(u1.w);
    } else {
      const float* Af = (const float*)Ap;
      float4 v0 = *(const float4*)(Af + arow0 + k0);
      float4 v1 = *(const float4*)(Af + arow1 + k0);
      a0[0]=v0.x; a0[1]=v0.y; a0[2]=v0.z; a0[3]=v0.w;
      a1[0]=v1.x; a1[1]=v1.y; a1[2]=v1.z; a1[3]=v1.w;
    }
    if (BT) {
      w0  = *(const float4*)(Bmat + (size_t)(n0 + b_r) * K + k0 + b_o);
      w1v = *(const float4*)(Bmat + (size_t)(n0 + b_r + 64) * K + k0 + b_o);
    } else {
      w0  = *(const float4*)(Bmat + (size_t)(k0 + b_r) * N + n0 + b_o);
      w1v = *(const float4*)(Bmat + (size_t)(k0 + b_r) * N + n0 + b_o + 64);
    }
  };
  load_tile(0);

  for (int k0 = 0; k0 < K; k0 += 16) {
    __syncthreads();
    As[ak+0][ar] = a0[0]; As[ak+1][ar] = a0[1]; As[ak+2][ar] = a0[2]; As[ak+3][ar] = a0[3];
    As[ak+0][ar+64] = a1[0]; As[ak+1][ar+64] = a1[1]; As[ak+2][ar+64] = a1[2]; As[ak+3][ar+64] = a1[3];
    if (BT) {
      Bs[b_o+0][b_r] = w0.x; Bs[b_o+1][b_r] = w0.y; Bs[b_o+2][b_r] = w0.z; Bs[b_o+3][b_r] = w0.w;
      Bs[b_o+0][b_r+64] = w1v.x; Bs[b_o+1][b_r+64] = w1v.y; Bs[b_o+2][b_r+64] = w1v.z; Bs[b_o+3][b_r+64] = w1v.w;
    } else {
      *(float4*)&Bs[b_r][b_o]      = w0;
      *(float4*)&Bs[b_r][b_o + 64] = w1v;
    }
    __syncthreads();
    // software pipeline: issue next tile's global loads, hidden under compute
    if (k0 + 16 < K) load_tile(k0 + 16);
    #pragma unroll
    for (int kk = 0; kk < 16; ++kk) {
      float av[8], bv[8];
      *(float4*)&av[0] = *(const float4*)&As[kk][ty * 8];
      *(float4*)&av[4] = *(const float4*)&As[kk][ty * 8 + 4];
      *(float4*)&bv[0] = *(const float4*)&Bs[kk][tx * 4];
      *(float4*)&bv[4] = *(const float4*)&Bs[kk][tx * 4 + 64];
      #pragma unroll
      for (int i = 0; i < 8; ++i)
        #pragma unroll
        for (int j = 0; j < 8; ++j)
          acc[i][j] = fmaf(av[i], bv[j], acc[i][j]);
    }
  }

  #pragma unroll
  for (int i = 0; i < 8; ++i) {
    int rloc = m0 + ty * 8 + i;
    if (MOE && rloc >= M) continue;
    size_t crow = (size_t)(rloc + (MOE ? rowOff : 0)) * N;
    #pragma unroll
    for (int half = 0; half < 2; ++half) {
      int c = n0 + half * 64 + tx * 4;
      float v[4];
      #pragma unroll
      for (int j = 0; j < 4; ++j) {
        v[j] = acc[i][half * 4 + j];
        if (BIAS) v[j] += biasp[c + j];
        if (RES)  v[j] += Rp[(size_t)rloc * N + c + j];
        if (RELU) v[j] = v[j] > 0.f ? v[j] : 0.f;
      }
      if (BF16OUT) {
        ushort4 u;
        u.x = f2bf(v[0]); u.y = f2bf(v[1]); u.z = f2bf(v[2]); u.w = f2bf(v[3]);
        *(ushort4*)((unsigned short*)Cp + crow + c) = u;
      } else {
        *(float4*)((float*)Cp + crow + c) = make_float4(v[0], v[1], v[2], v[3]);
      }
    }
  }
}

// ---------------- Flash attention, f32, hd=64, 64-row Q tiles ----------------
// 48 KB LDS (PsT aliased onto KsT, +1 barrier) -> 3 blocks/CU.
// PsT XOR-swizzled in 16B groups: 16-way write conflict -> 4-way.
// K/V tile kt+1 register-pipelined under compute of tile kt.
__global__ __launch_bounds__(256) void flash_kernel(
    const float* __restrict__ qkv, float* __restrict__ attn_out) {
  __shared__ float QsT[64][64];   // [d][row]
  __shared__ float KsT[64][64];   // [d][kv]; reused as swizzled P after S
  __shared__ float Vs[64][64];    // [kv][d]
  float* Ps = &KsT[0][0];

  // XCD swizzle: each XCD gets 4 (b,h) pairs x all q-tiles -> K/V L2-resident
  int bid = blockIdx.y * 32 + blockIdx.x;   // grid (32, 32), 1024 blocks
  int swz = (bid & 7) * 128 + (bid >> 3);
  const int bh = swz >> 5;
  const int qt = swz & 31;
  const int b = bh >> 3, h = bh & 7;
  const int t = threadIdx.x;
  const int tx = t & 15, ty = t >> 4;
  const int lr = t >> 2;            // tile row 0..63 for loads
  const int dbase = (t & 3) * 16;   // 16 d per thread

  {
    int l = qt * 64 + lr;
    const float* qrow = qkv + ((size_t)(l * kB + b)) * (3 * kE) + h * kHD;
    #pragma unroll
    for (int j = 0; j < 4; ++j) {
      float4 v = *(const float4*)(qrow + dbase + 4 * j);
      int d = dbase + 4 * j;
      QsT[d+0][lr] = v.x * 0.125f;
      QsT[d+1][lr] = v.y * 0.125f;
      QsT[d+2][lr] = v.z * 0.125f;
      QsT[d+3][lr] = v.w * 0.125f;
    }
  }

  float m_i[4], l_i[4], Oa[4][4];
  #pragma unroll
  for (int i = 0; i < 4; ++i) {
    m_i[i] = -1e30f; l_i[i] = 0.f;
    #pragma unroll
    for (int j = 0; j < 4; ++j) Oa[i][j] = 0.f;
  }

  float4 kreg[4], vreg[4];
  {
    const float* kro = qkv + ((size_t)((0 + lr) * kB + b)) * (3 * kE) + kE + h * kHD;
    const float* vro = kro + kE;
    #pragma unroll
    for (int j = 0; j < 4; ++j) {
      kreg[j] = *(const float4*)(kro + dbase + 4 * j);
      vreg[j] = *(const float4*)(vro + dbase + 4 * j);
    }
  }

  for (int kt = 0; kt < 32; ++kt) {
    __syncthreads();                 // prior PV reads of Ps/Vs complete
    #pragma unroll
    for (int j = 0; j < 4; ++j) {
      int d = dbase + 4 * j;
      KsT[d+0][lr] = kreg[j].x; KsT[d+1][lr] = kreg[j].y;
      KsT[d+2][lr] = kreg[j].z; KsT[d+3][lr] = kreg[j].w;
      *(float4*)&Vs[lr][d] = vreg[j];
    }
    __syncthreads();
    if (kt + 1 < 32) {               // pipeline next K/V tile into registers
      int l = (kt + 1) * 64 + lr;
      const float* kro = qkv + ((size_t)(l * kB + b)) * (3 * kE) + kE + h * kHD;
      const float* vro = kro + kE;
      #pragma unroll
      for (int j = 0; j < 4; ++j) {
        kreg[j] = *(const float4*)(kro + dbase + 4 * j);
        vreg[j] = *(const float4*)(vro + dbase + 4 * j);
      }
    }

    float S[4][4];
    #pragma unroll
    for (int i = 0; i < 4; ++i)
      #pragma unroll
      for (int j = 0; j < 4; ++j) S[i][j] = 0.f;
    #pragma unroll 8
    for (int d = 0; d < 64; ++d) {
      float4 qv = *(const float4*)&QsT[d][ty * 4];
      float4 kv = *(const float4*)&KsT[d][tx * 4];
      float qa[4] = {qv.x, qv.y, qv.z, qv.w};
      float ka[4] = {kv.x, kv.y, kv.z, kv.w};
      #pragma unroll
      for (int i = 0; i < 4; ++i)
        #pragma unroll
        for (int j = 0; j < 4; ++j) S[i][j] = fmaf(qa[i], ka[j], S[i][j]);
    }

    float alpha[4];
    #pragma unroll
    for (int i = 0; i < 4; ++i) {
      float tm = fmaxf(fmaxf(S[i][0], S[i][1]), fmaxf(S[i][2], S[i][3]));
      #pragma unroll
      for (int m = 1; m < 16; m <<= 1) tm = fmaxf(tm, __shfl_xor(tm, m));
      float mn = fmaxf(m_i[i], tm);
      alpha[i] = expf(m_i[i] - mn);
      m_i[i] = mn;
      float rs = 0.f;
      #pragma unroll
      for (int j = 0; j < 4; ++j) { S[i][j] = expf(S[i][j] - mn); rs += S[i][j]; }
      #pragma unroll
      for (int m = 1; m < 16; m <<= 1) rs += __shfl_xor(rs, m);
      l_i[i] = l_i[i] * alpha[i] + rs;
    }
    __syncthreads();                 // all KsT reads done before P overwrite
    #pragma unroll
    for (int i = 0; i < 4; ++i)
      #pragma unroll
      for (int j = 0; j < 4; ++j) {
        int c = tx * 4 + j;
        Ps[c * 64 + ((ty ^ (c & 15)) << 2) + i] = S[i][j];
      }
    __syncthreads();

    #pragma unroll
    for (int i = 0; i < 4; ++i)
      #pragma unroll
      for (int j = 0; j < 4; ++j) Oa[i][j] *= alpha[i];
    #pragma unroll 8
    for (int kv = 0; kv < 64; ++kv) {
      float4 pv = *(const float4*)&Ps[kv * 64 + ((ty ^ (kv & 15)) << 2)];
      float4 vv = *(const float4*)&Vs[kv][tx * 4];
      float pa[4] = {pv.x, pv.y, pv.z, pv.w};
      float va[4] = {vv.x, vv.y, vv.z, vv.w};
      #pragma unroll
      for (int i = 0; i < 4; ++i)
        #pragma unroll
        for (int j = 0; j < 4; ++j) Oa[i][j] = fmaf(pa[i], va[j], Oa[i][j]);
    }
  }

  #pragma unroll
  for (int i = 0; i < 4; ++i) {
    int l = qt * 64 + ty * 4 + i;
    float inv = 1.0f / l_i[i];
    float4 o = make_float4(Oa[i][0]*inv, Oa[i][1]*inv, Oa[i][2]*inv, Oa[i][3]*inv);
    *(float4*)(attn_out + ((size_t)(l * kB + b)) * kE + h * kHD + tx * 4) = o;
  }
}

// ---------------- Gating: logits, softmax, top2, partitionable-XOR threefry --
__global__ __launch_bounds__(256) void gating_kernel(
    const float* __restrict__ h2, const float* __restrict__ wg,
    int* __restrict__ e1, int* __restrict__ e2,
    float* __restrict__ g1, float* __restrict__ g2,
    int* __restrict__ keepr) {
  __shared__ float swg[kE * kNE];
  for (int i = threadIdx.x; i < kE * kNE; i += 256) swg[i] = wg[i];
  __syncthreads();
  int w = threadIdx.x >> 6, lane = threadIdx.x & 63;
  int tok = blockIdx.x * 4 + w;
  const float* xr = h2 + (size_t)tok * kE;
  float a0=0,a1=0,a2=0,a3=0,a4=0;
  for (int d = lane; d < kE; d += 64) {
    float xv = xr[d];
    a0 = fmaf(xv, swg[d*5+0], a0);
    a1 = fmaf(xv, swg[d*5+1], a1);
    a2 = fmaf(xv, swg[d*5+2], a2);
    a3 = fmaf(xv, swg[d*5+3], a3);
    a4 = fmaf(xv, swg[d*5+4], a4);
  }
  #pragma unroll
  for (int m = 32; m; m >>= 1) {
    a0 += __shfl_xor(a0, m); a1 += __shfl_xor(a1, m); a2 += __shfl_xor(a2, m);
    a3 += __shfl_xor(a3, m); a4 += __shfl_xor(a4, m);
  }
  if (lane == 0) {
    float lg[5] = {a0, a1, a2, a3, a4};
    float mx = lg[0];
    #pragma unroll
    for (int e = 1; e < 5; ++e) mx = fmaxf(mx, lg[e]);
    float ex[5], ssum = 0.f;
    #pragma unroll
    for (int e = 0; e < 5; ++e) { ex[e] = expf(lg[e] - mx); ssum += ex[e]; }
    float raw[5];
    #pragma unroll
    for (int e = 0; e < 5; ++e) raw[e] = ex[e] / ssum;
    int i1 = 0; float v1 = raw[0];
    #pragma unroll
    for (int e = 1; e < 5; ++e) if (raw[e] > v1) { v1 = raw[e]; i1 = e; }
    int i2 = 0; float v2 = -1.f;
    #pragma unroll
    for (int e = 0; e < 5; ++e) if (e != i1 && raw[e] > v2) { v2 = raw[e]; i2 = e; }
    float denom = v1 + v2 + 1e-9f;
    float G1 = v1 / denom, G2 = v2 / denom;
    // JAX partitionable threefry, 32-bit: bits = x0 ^ x1, counter (0, tok).
    unsigned x0 = 0u, x1 = (unsigned)tok;
    threefry(x0, x1);
    unsigned bits = x0 ^ x1;
    float u = __uint_as_float((bits >> 9) | 0x3F800000u) - 1.0f;
    int kr = (u < G2 / 0.2f) ? 1 : 0;
    e1[tok] = i1; e2[tok] = i2; g1[tok] = G1; g2[tok] = G2; keepr[tok] = kr;
  }
}

// ---------------- Per-group plan: positions + capacity -----------------------
__global__ __launch_bounds__(256) void plan_kernel(
    const int* __restrict__ e1, const int* __restrict__ e2,
    const int* __restrict__ keepr,
    int* __restrict__ slot1, int* __restrict__ slot2, int* __restrict__ tot) {
  int l = blockIdx.x * blockDim.x + threadIdx.x;
  if (l >= kL) return;
  int base = l * 4;
  int e1v[4], e2v[4], kr[4];
  #pragma unroll
  for (int n = 0; n < 4; ++n) {
    e1v[n] = e1[base + n]; e2v[n] = e2[base + n]; kr[n] = keepr[base + n];
  }
  int c1[5] = {0,0,0,0,0};
  int s1[4];
  #pragma unroll
  for (int n = 0; n < 4; ++n) {
    int e = e1v[n];
    int p = 0;
    #pragma unroll
    for (int q = 0; q < 5; ++q) if (q == e) p = c1[q];
    s1[n] = p;
    #pragma unroll
    for (int q = 0; q < 5; ++q) c1[q] += (q == e);
  }
  int run[5] = {0,0,0,0,0}, adm[5] = {0,0,0,0,0};
  int s2[4];
  #pragma unroll
  for (int n = 0; n < 4; ++n) {
    s2[n] = -1;
    if (kr[n]) {
      int e = e2v[n];
      int p = 0;
      #pragma unroll
      for (int q = 0; q < 5; ++q) if (q == e) p = c1[q] + run[q];
      if (p < kCAP) {
        s2[n] = p;
        #pragma unroll
        for (int q = 0; q < 5; ++q) adm[q] += (q == e);
      }
      #pragma unroll
      for (int q = 0; q < 5; ++q) run[q] += (q == e);
    }
  }
  #pragma unroll
  for (int n = 0; n < 4; ++n) { slot1[base + n] = s1[n]; slot2[base + n] = s2[n]; }
  #pragma unroll
  for (int q = 0; q < 5; ++q) tot[l * kNE + q] = c1[q] + adm[q];
}

// ---------------- Per-expert exclusive scan of group totals ------------------
__global__ __launch_bounds__(256) void scan_kernel(
    const int* __restrict__ tot, int* __restrict__ gbase, int* __restrict__ cnt) {
  int e = blockIdx.x;       // one block per expert
  int t = threadIdx.x;
  int lane = t & 63, w = t >> 6;
  __shared__ int wsum[4];
  __shared__ int carry;
  if (t == 0) carry = 0;
  __syncthreads();
  for (int chunk = 0; chunk < kL / 256; ++chunk) {
    int g = chunk * 256 + t;
    int v = tot[g * kNE + e];
    int inc = v;
    #pragma unroll
    for (int off = 1; off < 64; off <<= 1) {
      int u = __shfl_up(inc, off);
      if (lane >= off) inc += u;
    }
    if (lane == 63) wsum[w] = inc;
    __syncthreads();
    int wb = 0;
    #pragma unroll
    for (int i = 0; i < 4; ++i) wb += (i < w) ? wsum[i] : 0;
    int total = wsum[0] + wsum[1] + wsum[2] + wsum[3];
    gbase[g * kNE + e] = carry + wb + inc - v;
    __syncthreads();
    if (t == 0) carry += total;
    __syncthreads();
  }
  if (t == 0) cnt[e] = carry;
}

__global__ void bases_kernel(const int* __restrict__ cnt, int* __restrict__ base) {
  if (threadIdx.x == 0 && blockIdx.x == 0) {
    int a = 0;
    #pragma unroll
    for (int e = 0; e < kNE; ++e) { base[e] = a; a += cnt[e]; }
  }
}

// ---------------- Row map: token -> expert-buffer rows (and inverse) ---------
__global__ __launch_bounds__(256) void rowmap_kernel(
    const int* __restrict__ e1, const int* __restrict__ e2,
    const int* __restrict__ slot1, const int* __restrict__ slot2,
    const int* __restrict__ gbase, const int* __restrict__ ebase,
    int* __restrict__ rowOf1, int* __restrict__ rowOf2,
    int* __restrict__ tokOfRow) {
  int tok = blockIdx.x * blockDim.x + threadIdx.x;
  if (tok >= kT) return;
  int l = tok >> 2;
  int a = e1[tok];
  int r1 = ebase[a] + gbase[l * kNE + a] + slot1[tok];
  rowOf1[tok] = r1;
  tokOfRow[r1] = tok;
  int s2 = slot2[tok];
  int r2 = -1;
  if (s2 >= 0) {
    int bq = e2[tok];
    r2 = ebase[bq] + gbase[l * kNE + bq] + s2;
    tokOfRow[r2] = tok;
  }
  rowOf2[tok] = r2;
}

// ---------------- Final combine: out = x_res + g1*eo[r1] + g2*eo[r2] ---------
__global__ __launch_bounds__(128) void combine_kernel(
    const float* __restrict__ xres, const float* __restrict__ eo,
    const float* __restrict__ g1, const float* __restrict__ g2,
    const int* __restrict__ rowOf1, const int* __restrict__ rowOf2,
    float* __restrict__ out) {
  int tok = blockIdx.x;
  int t = threadIdx.x;
  float4 o = *(const float4*)(xres + (size_t)tok * kE + t * 4);
  int p1 = rowOf1[tok];
  float G1 = g1[tok];
  float4 a = *(const float4*)(eo + (size_t)p1 * kE + t * 4);
  o.x += G1 * a.x; o.y += G1 * a.y; o.z += G1 * a.z; o.w += G1 * a.w;
  int p2 = rowOf2[tok];
  if (p2 >= 0) {
    float G2 = g2[tok];
    float4 c = *(const float4*)(eo + (size_t)p2 * kE + t * 4);
    o.x += G2 * c.x; o.y += G2 * c.y; o.z += G2 * c.z; o.w += G2 * c.w;
  }
  *(float4*)(out + (size_t)tok * kE + t * 4) = o;
}

}  // namespace

extern "C" void kernel_launch(void* const* d_in, const int* in_sizes, int n_in,
                              void* d_out, int out_size, void* d_ws, size_t ws_size,
                              hipStream_t stream) {
  (void)in_sizes; (void)n_in; (void)out_size;
  const float* x    = (const float*)d_in[0];
  const float* ln1w = (const float*)d_in[1];
  const float* ln1b = (const float*)d_in[2];
  const float* ln2w = (const float*)d_in[3];
  const float* ln2b = (const float*)d_in[4];
  const float* wqkv = (const float*)d_in[5];
  const float* bqkv = (const float*)d_in[6];
  const float* wo   = (const float*)d_in[7];
  const float* bo   = (const float*)d_in[8];
  const float* wg   = (const float*)d_in[9];
  const float* w1   = (const float*)d_in[10];
  const float* w2   = (const float*)d_in[11];
  float* out = (float*)d_out;

  // workspace layout (float units):
  // [0, 12582912)            qkv (T x 1536)
  // [12582912, 16777216)     h1 / attn_out (T x 512)
  //   -> region [0, 16777216) reused later as h_moe bf16 (16384 x 2048)
  // [16777216, 20971520)     x_res
  // [20971520, 25165824)     h2
  // [25165824, 33554432)     eo (16384 x 512 f32)
  // [33554432, ...)          int buffers
  if (ws_size < (size_t)135000000) return;  // need ~134.7 MB scratch
  float* ws   = (float*)d_ws;
  float* qkv  = ws;
  float* h1   = ws + 12582912;
  unsigned short* hmoe = (unsigned short*)ws;    // reuse, after attention done
  float* xres = ws + 16777216;
  float* h2   = ws + 20971520;
  float* eo   = ws + 25165824;
  int* ibuf    = (int*)(ws + 33554432);
  int* e1      = ibuf;                 // 8192
  int* e2      = e1 + kT;              // 8192
  float* g1f   = (float*)(e2 + kT);    // 8192
  float* g2f   = g1f + kT;             // 8192
  int* keepr   = (int*)(g2f + kT);     // 8192
  int* slot1   = keepr + kT;           // 8192
  int* slot2   = slot1 + kT;           // 8192
  int* rowOf1  = slot2 + kT;           // 8192
  int* rowOf2  = rowOf1 + kT;          // 8192
  int* tot     = rowOf2 + kT;          // 2048*5
  int* gbase   = tot + kL * kNE;       // 2048*5
  int* tokOfRow= gbase + kL * kNE;     // 16384
  int* cnt     = tokOfRow + 2 * kT;    // 8
  int* ebase   = cnt + 8;              // 8

  // 1. h1 = LN1(x)
  ln_kernel<<<kT, 256, 0, stream>>>(x, ln1w, ln1b, h1);
  // 2. qkv = h1 @ Wqkv^T + b  (M=8192, N=1536, K=512)
  gemm_kernel<1,0,0,1,0,0,0,0><<<dim3(12, 64, 1), 256, 0, stream>>>(
      h1, wqkv, bqkv, nullptr, qkv, kT, 1536, kE, nullptr, nullptr, nullptr, 0);
  // 3. attention (f32 flash), writes attn_out into h1
  flash_kernel<<<dim3(32, 32, 1), 256, 0, stream>>>(qkv, h1);
  // 4. x_res = x + attn_out @ Wo^T + bo  (M=8192, N=512, K=512)
  gemm_kernel<1,0,0,1,1,0,0,0><<<dim3(4, 64, 1), 256, 0, stream>>>(
      h1, wo, bo, x, xres, kT, kE, kE, nullptr, nullptr, nullptr, 0);
  // 5. h2 = LN2(x_res)
  ln_kernel<<<kT, 256, 0, stream>>>(xres, ln2w, ln2b, h2);
  // 6. gating per token (partitionable-XOR threefry — verified r8)
  gating_kernel<<<kL, 256, 0, stream>>>(h2, wg, e1, e2, g1f, g2f, keepr);
  // 7. per-group plan (positions + capacity)
  plan_kernel<<<kL / 256, 256, 0, stream>>>(e1, e2, keepr, slot1, slot2, tot);
  // 8. per-expert scan of group totals; expert bases; token->row maps
  scan_kernel<<<kNE, 256, 0, stream>>>(tot, gbase, cnt);
  bases_kernel<<<1, 32, 0, stream>>>(cnt, ebase);
  rowmap_kernel<<<kT / 256, 256, 0, stream>>>(
      e1, e2, slot1, slot2, gbase, ebase, rowOf1, rowOf2, tokOfRow);
  // 9. h_moe = relu(gather(h2) @ w1[e])  (N=2048, K=512) -> bf16
  gemm_kernel<0,1,1,0,0,1,0,1><<<dim3(16, 64, kNE), 256, 0, stream>>>(
      h2, w1, nullptr, nullptr, hmoe, 0, kFF, kE, tokOfRow, cnt, ebase, kE * kFF);
  // 10. eo = h_moe @ w2[e]  (N=512, K=2048), bf16 A
  gemm_kernel<0,1,0,0,0,0,1,0><<<dim3(4, 64, kNE), 256, 0, stream>>>(
      hmoe, w2, nullptr, nullptr, eo, 0, kE, kFF, nullptr, cnt, ebase, kFF * kE);
  // 11. out = x_res + g1*eo[r1] + g2*eo[r2]
  combine_kernel<<<kT, 128, 0, stream>>>(
      xres, eo, g1f, g2f, rowOf1, rowOf2, out);
}

// Round 11
// 1159.678 us; speedup vs baseline: 2.5671x; 2.5671x over previous
//
#include <hip/hip_runtime.h>

#define DI __device__ __forceinline__

namespace {

constexpr int kL  = 2048;
constexpr int kB  = 4;
constexpr int kE  = 512;
constexpr int kHD = 64;
constexpr int kFF = 2048;
constexpr int kNE = 5;
constexpr int kT  = 8192;   // kL * kB tokens
constexpr int kCAP = 4;

using bf16x8 = __attribute__((ext_vector_type(8))) short;
using f32x4  = __attribute__((ext_vector_type(4))) float;

DI float bf2f(unsigned short u) { return __uint_as_float(((unsigned)u) << 16); }
DI unsigned short f2bf(float f) {
  unsigned u = __float_as_uint(f);
  u = u + 0x7FFFu + ((u >> 16) & 1u);
  return (unsigned short)(u >> 16);
}

DI unsigned rotl(unsigned v, int d) { return (v << d) | (v >> (32 - d)); }

// JAX threefry2x32 with key = PRNGKey(42) = (0, 42), 20 rounds.
DI void threefry(unsigned& x0, unsigned& x1) {
  const unsigned K1 = 0u, K2 = 42u, K3 = 0x1BD11BDAu ^ 0u ^ 42u;
  x0 += K1; x1 += K2;
  x0 += x1; x1 = rotl(x1, 13); x1 ^= x0;
  x0 += x1; x1 = rotl(x1, 15); x1 ^= x0;
  x0 += x1; x1 = rotl(x1, 26); x1 ^= x0;
  x0 += x1; x1 = rotl(x1,  6); x1 ^= x0;
  x0 += K2; x1 += K3 + 1u;
  x0 += x1; x1 = rotl(x1, 17); x1 ^= x0;
  x0 += x1; x1 = rotl(x1, 29); x1 ^= x0;
  x0 += x1; x1 = rotl(x1, 16); x1 ^= x0;
  x0 += x1; x1 = rotl(x1, 24); x1 ^= x0;
  x0 += K3; x1 += K1 + 2u;
  x0 += x1; x1 = rotl(x1, 13); x1 ^= x0;
  x0 += x1; x1 = rotl(x1, 15); x1 ^= x0;
  x0 += x1; x1 = rotl(x1, 26); x1 ^= x0;
  x0 += x1; x1 = rotl(x1,  6); x1 ^= x0;
  x0 += K1; x1 += K2 + 3u;
  x0 += x1; x1 = rotl(x1, 17); x1 ^= x0;
  x0 += x1; x1 = rotl(x1, 29); x1 ^= x0;
  x0 += x1; x1 = rotl(x1, 16); x1 ^= x0;
  x0 += x1; x1 = rotl(x1, 24); x1 ^= x0;
  x0 += K2; x1 += K3 + 4u;
  x0 += x1; x1 = rotl(x1, 13); x1 ^= x0;
  x0 += x1; x1 = rotl(x1, 15); x1 ^= x0;
  x0 += x1; x1 = rotl(x1, 26); x1 ^= x0;
  x0 += x1; x1 = rotl(x1,  6); x1 ^= x0;
  x0 += K3; x1 += K1 + 5u;
}

// ---------------- f32 -> bf16 bulk convert -----------------------------------
__global__ __launch_bounds__(256) void f2bf_kernel(
    const float* __restrict__ src, unsigned short* __restrict__ dst, int n4) {
  int i = blockIdx.x * blockDim.x + threadIdx.x;
  if (i >= n4) return;
  float4 v = ((const float4*)src)[i];
  ushort4 u;
  u.x = f2bf(v.x); u.y = f2bf(v.y); u.z = f2bf(v.z); u.w = f2bf(v.w);
  ((ushort4*)dst)[i] = u;
}

// ---------------- LayerNorm (one row per block, 256 threads, E=512) -----------
__global__ __launch_bounds__(256) void ln_kernel(
    const float* __restrict__ x, const float* __restrict__ w,
    const float* __restrict__ b, float* __restrict__ out) {
  int row = blockIdx.x;
  const float* xr = x + (size_t)row * kE;
  int t = threadIdx.x;
  float2 v = *(const float2*)(xr + t * 2);
  __shared__ float red[4];
  float s = v.x + v.y;
  #pragma unroll
  for (int m = 32; m; m >>= 1) s += __shfl_xor(s, m);
  if ((t & 63) == 0) red[t >> 6] = s;
  __syncthreads();
  float mu = (red[0] + red[1] + red[2] + red[3]) * (1.0f / kE);
  float dx = v.x - mu, dy = v.y - mu;
  float q = dx * dx + dy * dy;
  #pragma unroll
  for (int m = 32; m; m >>= 1) q += __shfl_xor(q, m);
  __syncthreads();
  if ((t & 63) == 0) red[t >> 6] = q;
  __syncthreads();
  float var = (red[0] + red[1] + red[2] + red[3]) * (1.0f / kE);
  float inv = 1.0f / sqrtf(var + 1e-5f);
  float2 o;
  o.x = dx * inv * w[t * 2]     + b[t * 2];
  o.y = dy * inv * w[t * 2 + 1] + b[t * 2 + 1];
  *(float2*)(out + (size_t)row * kE + t * 2) = o;
}

// ---------------- 128x128 f32 GEMM, BT=1 (C=A*B^T), non-MOE only -------------
// XCD-swizzled (grid multiple of 8), register-pipelined staging.
template <int BIAS, int RES>
__global__ __launch_bounds__(256) void gemm_kernel(
    const float* __restrict__ Ap, const float* __restrict__ Bp,
    const float* __restrict__ biasp, const float* __restrict__ Rp,
    float* __restrict__ Cp, int M, int N, int K) {
  __shared__ float As[16][128];
  __shared__ float Bs[16][128];

  int nwg = gridDim.x * gridDim.y;
  int bid = blockIdx.y * gridDim.x + blockIdx.x;
  int swz = (bid & 7) * (nwg >> 3) + (bid >> 3);
  int wx = swz % gridDim.x, wy = swz / gridDim.x;

  const int m0 = wy * 128;
  const int n0 = wx * 128;
  const int t = threadIdx.x;
  const int tx = t & 15, ty = t >> 4;

  const int ar = t >> 2;         // 0..63
  const int ak = (t & 3) * 4;    // k offset 0/4/8/12
  size_t arow0 = (size_t)(m0 + ar) * K + ak;
  size_t arow1 = (size_t)(m0 + ar + 64) * K + ak;
  const int b_r = t >> 2, b_o = (t & 3) * 4;

  float acc[8][8];
  #pragma unroll
  for (int i = 0; i < 8; ++i)
    #pragma unroll
    for (int j = 0; j < 8; ++j) acc[i][j] = 0.0f;

  float4 v0r, v1r, w0, w1v;
  auto load_tile = [&](int k0) {
    v0r = *(const float4*)(Ap + arow0 + k0);
    v1r = *(const float4*)(Ap + arow1 + k0);
    w0  = *(const float4*)(Bp + (size_t)(n0 + b_r) * K + k0 + b_o);
    w1v = *(const float4*)(Bp + (size_t)(n0 + b_r + 64) * K + k0 + b_o);
  };
  load_tile(0);

  for (int k0 = 0; k0 < K; k0 += 16) {
    __syncthreads();
    As[ak+0][ar] = v0r.x; As[ak+1][ar] = v0r.y; As[ak+2][ar] = v0r.z; As[ak+3][ar] = v0r.w;
    As[ak+0][ar+64] = v1r.x; As[ak+1][ar+64] = v1r.y; As[ak+2][ar+64] = v1r.z; As[ak+3][ar+64] = v1r.w;
    Bs[b_o+0][b_r] = w0.x; Bs[b_o+1][b_r] = w0.y; Bs[b_o+2][b_r] = w0.z; Bs[b_o+3][b_r] = w0.w;
    Bs[b_o+0][b_r+64] = w1v.x; Bs[b_o+1][b_r+64] = w1v.y; Bs[b_o+2][b_r+64] = w1v.z; Bs[b_o+3][b_r+64] = w1v.w;
    __syncthreads();
    if (k0 + 16 < K) load_tile(k0 + 16);
    #pragma unroll
    for (int kk = 0; kk < 16; ++kk) {
      float av[8], bv[8];
      *(float4*)&av[0] = *(const float4*)&As[kk][ty * 8];
      *(float4*)&av[4] = *(const float4*)&As[kk][ty * 8 + 4];
      *(float4*)&bv[0] = *(const float4*)&Bs[kk][tx * 4];
      *(float4*)&bv[4] = *(const float4*)&Bs[kk][tx * 4 + 64];
      #pragma unroll
      for (int i = 0; i < 8; ++i)
        #pragma unroll
        for (int j = 0; j < 8; ++j)
          acc[i][j] = fmaf(av[i], bv[j], acc[i][j]);
    }
  }

  #pragma unroll
  for (int i = 0; i < 8; ++i) {
    int rloc = m0 + ty * 8 + i;
    size_t crow = (size_t)rloc * N;
    #pragma unroll
    for (int half = 0; half < 2; ++half) {
      int c = n0 + half * 64 + tx * 4;
      float v[4];
      #pragma unroll
      for (int j = 0; j < 4; ++j) {
        v[j] = acc[i][half * 4 + j];
        if (BIAS) v[j] += biasp[c + j];
        if (RES)  v[j] += Rp[crow + c + j];
      }
      *(float4*)(Cp + crow + c) = make_float4(v[0], v[1], v[2], v[3]);
    }
  }
}

// ---------------- MoE bf16 MFMA GEMM: C = [relu](gather(A) @ B[e]) -----------
// A: bf16 [rows][K]; B: bf16 [NE][K][N]; C: bf16 [rows][N], rows compacted.
// Tile 128x128, 4 waves (2x2), wave tile 64x64 = 4x4 frags of 16x16x32 MFMA.
// Natural block->XCD mapping (x%8): balanced across experts' M.
template <int GATHER, int RELU, int K, int N>
__global__ __launch_bounds__(256) void moe_mfma_kernel(
    const unsigned short* __restrict__ Abf, const unsigned short* __restrict__ Bbf,
    unsigned short* __restrict__ Cbf,
    const int* __restrict__ gatherp, const int* __restrict__ cntp,
    const int* __restrict__ basep) {
  __shared__ unsigned short As[128][40];   // [m][k] pad 32->40 (80B stride)
  __shared__ unsigned short Bs[128][40];   // [n][k] transposed

  const int e = blockIdx.z;
  const int M = cntp[e];
  const int rowOff = basep[e];
  if ((int)blockIdx.y * 128 >= M) return;
  const unsigned short* Bg = Bbf + (size_t)e * K * N;
  const int m0 = blockIdx.y * 128;
  const int n0 = blockIdx.x * 128;
  const int t = threadIdx.x;
  const int lane = t & 63, w = t >> 6;
  const int wm = w >> 1, wn = w & 1;

  // A staging: thread t -> row ar (0..127), half ah; 16 bf16 per thread
  const int ar = t >> 1, ah = t & 1;
  size_t abase;
  {
    int r = m0 + ar;
    int mm = M - 1; r = r < mm ? r : mm;
    if (GATHER) r = gatherp[rowOff + r];
    else        r += rowOff;
    abase = (size_t)r * K;
  }
  // B staging: thread t -> k row bk (0..31), 16 cols from bn
  const int bk = t >> 3, bn = (t & 7) * 16;

  f32x4 acc[4][4];
  #pragma unroll
  for (int i = 0; i < 4; ++i)
    #pragma unroll
    for (int j = 0; j < 4; ++j)
      acc[i][j] = (f32x4){0.f, 0.f, 0.f, 0.f};

  uint4 aR0, aR1, bR0, bR1;
  auto gload = [&](int k0) {
    aR0 = *(const uint4*)(Abf + abase + k0 + ah * 16);
    aR1 = *(const uint4*)(Abf + abase + k0 + ah * 16 + 8);
    bR0 = *(const uint4*)(Bg + (size_t)(k0 + bk) * N + n0 + bn);
    bR1 = *(const uint4*)(Bg + (size_t)(k0 + bk) * N + n0 + bn + 8);
  };
  gload(0);

  const int kg = (lane >> 4) * 8;   // k group for fragments
  const int mr = lane & 15;

  for (int k0 = 0; k0 < K; k0 += 32) {
    __syncthreads();
    *(uint4*)&As[ar][ah * 16]     = aR0;
    *(uint4*)&As[ar][ah * 16 + 8] = aR1;
    {
      unsigned short tmp[16];
      *(uint4*)tmp       = bR0;
      *(uint4*)(tmp + 8) = bR1;
      #pragma unroll
      for (int j = 0; j < 16; ++j) Bs[bn + j][bk] = tmp[j];
    }
    __syncthreads();
    if (k0 + 32 < K) gload(k0 + 32);

    bf16x8 af[4], bfr[4];
    #pragma unroll
    for (int i = 0; i < 4; ++i)
      af[i] = *(const bf16x8*)&As[wm * 64 + i * 16 + mr][kg];
    #pragma unroll
    for (int j = 0; j < 4; ++j)
      bfr[j] = *(const bf16x8*)&Bs[wn * 64 + j * 16 + mr][kg];
    #pragma unroll
    for (int i = 0; i < 4; ++i)
      #pragma unroll
      for (int j = 0; j < 4; ++j)
        acc[i][j] = __builtin_amdgcn_mfma_f32_16x16x32_bf16(
            af[i], bfr[j], acc[i][j], 0, 0, 0);
  }

  // C write: frag (i,j): row = m0+wm*64+i*16+(lane>>4)*4+r, col = n0+wn*64+j*16+(lane&15)
  const int lr4 = (lane >> 4) * 4;
  const int lc = lane & 15;
  #pragma unroll
  for (int i = 0; i < 4; ++i)
    #pragma unroll
    for (int r = 0; r < 4; ++r) {
      int row = m0 + wm * 64 + i * 16 + lr4 + r;
      if (row >= M) continue;
      size_t crow = (size_t)(row + rowOff) * N;
      #pragma unroll
      for (int j = 0; j < 4; ++j) {
        float v = acc[i][j][r];
        if (RELU) v = v > 0.f ? v : 0.f;
        Cbf[crow + n0 + wn * 64 + j * 16 + lc] = f2bf(v);
      }
    }
}

// ---------------- Flash attention, f32, hd=64, 64-row Q tiles ----------------
__global__ __launch_bounds__(256) void flash_kernel(
    const float* __restrict__ qkv, float* __restrict__ attn_out) {
  __shared__ float QsT[64][64];   // [d][row]
  __shared__ float KsT[64][64];   // [d][kv]; reused as swizzled P after S
  __shared__ float Vs[64][64];    // [kv][d]
  float* Ps = &KsT[0][0];

  int bid = blockIdx.y * 32 + blockIdx.x;   // grid (32, 32), 1024 blocks
  int swz = (bid & 7) * 128 + (bid >> 3);
  const int bh = swz >> 5;
  const int qt = swz & 31;
  const int b = bh >> 3, h = bh & 7;
  const int t = threadIdx.x;
  const int tx = t & 15, ty = t >> 4;
  const int lr = t >> 2;
  const int dbase = (t & 3) * 16;

  {
    int l = qt * 64 + lr;
    const float* qrow = qkv + ((size_t)(l * kB + b)) * (3 * kE) + h * kHD;
    #pragma unroll
    for (int j = 0; j < 4; ++j) {
      float4 v = *(const float4*)(qrow + dbase + 4 * j);
      int d = dbase + 4 * j;
      QsT[d+0][lr] = v.x * 0.125f;
      QsT[d+1][lr] = v.y * 0.125f;
      QsT[d+2][lr] = v.z * 0.125f;
      QsT[d+3][lr] = v.w * 0.125f;
    }
  }

  float m_i[4], l_i[4], Oa[4][4];
  #pragma unroll
  for (int i = 0; i < 4; ++i) {
    m_i[i] = -1e30f; l_i[i] = 0.f;
    #pragma unroll
    for (int j = 0; j < 4; ++j) Oa[i][j] = 0.f;
  }

  float4 kreg[4], vreg[4];
  {
    const float* kro = qkv + ((size_t)(lr * kB + b)) * (3 * kE) + kE + h * kHD;
    const float* vro = kro + kE;
    #pragma unroll
    for (int j = 0; j < 4; ++j) {
      kreg[j] = *(const float4*)(kro + dbase + 4 * j);
      vreg[j] = *(const float4*)(vro + dbase + 4 * j);
    }
  }

  for (int kt = 0; kt < 32; ++kt) {
    __syncthreads();
    #pragma unroll
    for (int j = 0; j < 4; ++j) {
      int d = dbase + 4 * j;
      KsT[d+0][lr] = kreg[j].x; KsT[d+1][lr] = kreg[j].y;
      KsT[d+2][lr] = kreg[j].z; KsT[d+3][lr] = kreg[j].w;
      *(float4*)&Vs[lr][d] = vreg[j];
    }
    __syncthreads();
    if (kt + 1 < 32) {
      int l = (kt + 1) * 64 + lr;
      const float* kro = qkv + ((size_t)(l * kB + b)) * (3 * kE) + kE + h * kHD;
      const float* vro = kro + kE;
      #pragma unroll
      for (int j = 0; j < 4; ++j) {
        kreg[j] = *(const float4*)(kro + dbase + 4 * j);
        vreg[j] = *(const float4*)(vro + dbase + 4 * j);
      }
    }

    float S[4][4];
    #pragma unroll
    for (int i = 0; i < 4; ++i)
      #pragma unroll
      for (int j = 0; j < 4; ++j) S[i][j] = 0.f;
    #pragma unroll 8
    for (int d = 0; d < 64; ++d) {
      float4 qv = *(const float4*)&QsT[d][ty * 4];
      float4 kv = *(const float4*)&KsT[d][tx * 4];
      float qa[4] = {qv.x, qv.y, qv.z, qv.w};
      float ka[4] = {kv.x, kv.y, kv.z, kv.w};
      #pragma unroll
      for (int i = 0; i < 4; ++i)
        #pragma unroll
        for (int j = 0; j < 4; ++j) S[i][j] = fmaf(qa[i], ka[j], S[i][j]);
    }

    float alpha[4];
    #pragma unroll
    for (int i = 0; i < 4; ++i) {
      float tm = fmaxf(fmaxf(S[i][0], S[i][1]), fmaxf(S[i][2], S[i][3]));
      #pragma unroll
      for (int m = 1; m < 16; m <<= 1) tm = fmaxf(tm, __shfl_xor(tm, m));
      float mn = fmaxf(m_i[i], tm);
      alpha[i] = expf(m_i[i] - mn);
      m_i[i] = mn;
      float rs = 0.f;
      #pragma unroll
      for (int j = 0; j < 4; ++j) { S[i][j] = expf(S[i][j] - mn); rs += S[i][j]; }
      #pragma unroll
      for (int m = 1; m < 16; m <<= 1) rs += __shfl_xor(rs, m);
      l_i[i] = l_i[i] * alpha[i] + rs;
    }
    __syncthreads();
    #pragma unroll
    for (int i = 0; i < 4; ++i)
      #pragma unroll
      for (int j = 0; j < 4; ++j) {
        int c = tx * 4 + j;
        Ps[c * 64 + ((ty ^ (c & 15)) << 2) + i] = S[i][j];
      }
    __syncthreads();

    #pragma unroll
    for (int i = 0; i < 4; ++i)
      #pragma unroll
      for (int j = 0; j < 4; ++j) Oa[i][j] *= alpha[i];
    #pragma unroll 8
    for (int kv = 0; kv < 64; ++kv) {
      float4 pv = *(const float4*)&Ps[kv * 64 + ((ty ^ (kv & 15)) << 2)];
      float4 vv = *(const float4*)&Vs[kv][tx * 4];
      float pa[4] = {pv.x, pv.y, pv.z, pv.w};
      float va[4] = {vv.x, vv.y, vv.z, vv.w};
      #pragma unroll
      for (int i = 0; i < 4; ++i)
        #pragma unroll
        for (int j = 0; j < 4; ++j) Oa[i][j] = fmaf(pa[i], va[j], Oa[i][j]);
    }
  }

  #pragma unroll
  for (int i = 0; i < 4; ++i) {
    int l = qt * 64 + ty * 4 + i;
    float inv = 1.0f / l_i[i];
    float4 o = make_float4(Oa[i][0]*inv, Oa[i][1]*inv, Oa[i][2]*inv, Oa[i][3]*inv);
    *(float4*)(attn_out + ((size_t)(l * kB + b)) * kE + h * kHD + tx * 4) = o;
  }
}

// ---------------- Gating: logits, softmax, top2, partitionable-XOR threefry --
__global__ __launch_bounds__(256) void gating_kernel(
    const float* __restrict__ h2, const float* __restrict__ wg,
    int* __restrict__ e1, int* __restrict__ e2,
    float* __restrict__ g1, float* __restrict__ g2,
    int* __restrict__ keepr) {
  __shared__ float swg[kE * kNE];
  for (int i = threadIdx.x; i < kE * kNE; i += 256) swg[i] = wg[i];
  __syncthreads();
  int w = threadIdx.x >> 6, lane = threadIdx.x & 63;
  int tok = blockIdx.x * 4 + w;
  const float* xr = h2 + (size_t)tok * kE;
  float a0=0,a1=0,a2=0,a3=0,a4=0;
  for (int d = lane; d < kE; d += 64) {
    float xv = xr[d];
    a0 = fmaf(xv, swg[d*5+0], a0);
    a1 = fmaf(xv, swg[d*5+1], a1);
    a2 = fmaf(xv, swg[d*5+2], a2);
    a3 = fmaf(xv, swg[d*5+3], a3);
    a4 = fmaf(xv, swg[d*5+4], a4);
  }
  #pragma unroll
  for (int m = 32; m; m >>= 1) {
    a0 += __shfl_xor(a0, m); a1 += __shfl_xor(a1, m); a2 += __shfl_xor(a2, m);
    a3 += __shfl_xor(a3, m); a4 += __shfl_xor(a4, m);
  }
  if (lane == 0) {
    float lg[5] = {a0, a1, a2, a3, a4};
    float mx = lg[0];
    #pragma unroll
    for (int e = 1; e < 5; ++e) mx = fmaxf(mx, lg[e]);
    float ex[5], ssum = 0.f;
    #pragma unroll
    for (int e = 0; e < 5; ++e) { ex[e] = expf(lg[e] - mx); ssum += ex[e]; }
    float raw[5];
    #pragma unroll
    for (int e = 0; e < 5; ++e) raw[e] = ex[e] / ssum;
    int i1 = 0; float v1 = raw[0];
    #pragma unroll
    for (int e = 1; e < 5; ++e) if (raw[e] > v1) { v1 = raw[e]; i1 = e; }
    int i2 = 0; float v2 = -1.f;
    #pragma unroll
    for (int e = 0; e < 5; ++e) if (e != i1 && raw[e] > v2) { v2 = raw[e]; i2 = e; }
    float denom = v1 + v2 + 1e-9f;
    float G1 = v1 / denom, G2 = v2 / denom;
    // JAX partitionable threefry, 32-bit: bits = x0 ^ x1, counter (0, tok).
    unsigned x0 = 0u, x1 = (unsigned)tok;
    threefry(x0, x1);
    unsigned bits = x0 ^ x1;
    float u = __uint_as_float((bits >> 9) | 0x3F800000u) - 1.0f;
    int kr = (u < G2 / 0.2f) ? 1 : 0;
    e1[tok] = i1; e2[tok] = i2; g1[tok] = G1; g2[tok] = G2; keepr[tok] = kr;
  }
}

// ---------------- Per-group plan: positions + capacity -----------------------
__global__ __launch_bounds__(256) void plan_kernel(
    const int* __restrict__ e1, const int* __restrict__ e2,
    const int* __restrict__ keepr,
    int* __restrict__ slot1, int* __restrict__ slot2, int* __restrict__ tot) {
  int l = blockIdx.x * blockDim.x + threadIdx.x;
  if (l >= kL) return;
  int base = l * 4;
  int e1v[4], e2v[4], kr[4];
  #pragma unroll
  for (int n = 0; n < 4; ++n) {
    e1v[n] = e1[base + n]; e2v[n] = e2[base + n]; kr[n] = keepr[base + n];
  }
  int c1[5] = {0,0,0,0,0};
  int s1[4];
  #pragma unroll
  for (int n = 0; n < 4; ++n) {
    int e = e1v[n];
    int p = 0;
    #pragma unroll
    for (int q = 0; q < 5; ++q) if (q == e) p = c1[q];
    s1[n] = p;
    #pragma unroll
    for (int q = 0; q < 5; ++q) c1[q] += (q == e);
  }
  int run[5] = {0,0,0,0,0}, adm[5] = {0,0,0,0,0};
  int s2[4];
  #pragma unroll
  for (int n = 0; n < 4; ++n) {
    s2[n] = -1;
    if (kr[n]) {
      int e = e2v[n];
      int p = 0;
      #pragma unroll
      for (int q = 0; q < 5; ++q) if (q == e) p = c1[q] + run[q];
      if (p < kCAP) {
        s2[n] = p;
        #pragma unroll
        for (int q = 0; q < 5; ++q) adm[q] += (q == e);
      }
      #pragma unroll
      for (int q = 0; q < 5; ++q) run[q] += (q == e);
    }
  }
  #pragma unroll
  for (int n = 0; n < 4; ++n) { slot1[base + n] = s1[n]; slot2[base + n] = s2[n]; }
  #pragma unroll
  for (int q = 0; q < 5; ++q) tot[l * kNE + q] = c1[q] + adm[q];
}

// ---------------- Per-expert exclusive scan of group totals ------------------
__global__ __launch_bounds__(256) void scan_kernel(
    const int* __restrict__ tot, int* __restrict__ gbase, int* __restrict__ cnt) {
  int e = blockIdx.x;       // one block per expert
  int t = threadIdx.x;
  int lane = t & 63, w = t >> 6;
  __shared__ int wsum[4];
  __shared__ int carry;
  if (t == 0) carry = 0;
  __syncthreads();
  for (int chunk = 0; chunk < kL / 256; ++chunk) {
    int g = chunk * 256 + t;
    int v = tot[g * kNE + e];
    int inc = v;
    #pragma unroll
    for (int off = 1; off < 64; off <<= 1) {
      int u = __shfl_up(inc, off);
      if (lane >= off) inc += u;
    }
    if (lane == 63) wsum[w] = inc;
    __syncthreads();
    int wb = 0;
    #pragma unroll
    for (int i = 0; i < 4; ++i) wb += (i < w) ? wsum[i] : 0;
    int total = wsum[0] + wsum[1] + wsum[2] + wsum[3];
    gbase[g * kNE + e] = carry + wb + inc - v;
    __syncthreads();
    if (t == 0) carry += total;
    __syncthreads();
  }
  if (t == 0) cnt[e] = carry;
}

__global__ void bases_kernel(const int* __restrict__ cnt, int* __restrict__ base) {
  if (threadIdx.x == 0 && blockIdx.x == 0) {
    int a = 0;
    #pragma unroll
    for (int e = 0; e < kNE; ++e) { base[e] = a; a += cnt[e]; }
  }
}

// ---------------- Row map: token -> expert-buffer rows -----------------------
__global__ __launch_bounds__(256) void rowmap_kernel(
    const int* __restrict__ e1, const int* __restrict__ e2,
    const int* __restrict__ slot1, const int* __restrict__ slot2,
    const int* __restrict__ gbase, const int* __restrict__ ebase,
    int* __restrict__ rowOf1, int* __restrict__ rowOf2,
    int* __restrict__ tokOfRow) {
  int tok = blockIdx.x * blockDim.x + threadIdx.x;
  if (tok >= kT) return;
  int l = tok >> 2;
  int a = e1[tok];
  int r1 = ebase[a] + gbase[l * kNE + a] + slot1[tok];
  rowOf1[tok] = r1;
  tokOfRow[r1] = tok;
  int s2 = slot2[tok];
  int r2 = -1;
  if (s2 >= 0) {
    int bq = e2[tok];
    r2 = ebase[bq] + gbase[l * kNE + bq] + s2;
    tokOfRow[r2] = tok;
  }
  rowOf2[tok] = r2;
}

// ---------------- Final combine: out = x_res + g1*eo[r1] + g2*eo[r2] ---------
__global__ __launch_bounds__(128) void combine_kernel(
    const float* __restrict__ xres, const unsigned short* __restrict__ eo,
    const float* __restrict__ g1, const float* __restrict__ g2,
    const int* __restrict__ rowOf1, const int* __restrict__ rowOf2,
    float* __restrict__ out) {
  int tok = blockIdx.x;
  int t = threadIdx.x;
  float4 o = *(const float4*)(xres + (size_t)tok * kE + t * 4);
  int p1 = rowOf1[tok];
  float G1 = g1[tok];
  ushort4 a = *(const ushort4*)(eo + (size_t)p1 * kE + t * 4);
  o.x += G1 * bf2f(a.x); o.y += G1 * bf2f(a.y);
  o.z += G1 * bf2f(a.z); o.w += G1 * bf2f(a.w);
  int p2 = rowOf2[tok];
  if (p2 >= 0) {
    float G2 = g2[tok];
    ushort4 c = *(const ushort4*)(eo + (size_t)p2 * kE + t * 4);
    o.x += G2 * bf2f(c.x); o.y += G2 * bf2f(c.y);
    o.z += G2 * bf2f(c.z); o.w += G2 * bf2f(c.w);
  }
  *(float4*)(out + (size_t)tok * kE + t * 4) = o;
}

}  // namespace

extern "C" void kernel_launch(void* const* d_in, const int* in_sizes, int n_in,
                              void* d_out, int out_size, void* d_ws, size_t ws_size,
                              hipStream_t stream) {
  (void)in_sizes; (void)n_in; (void)out_size;
  const float* x    = (const float*)d_in[0];
  const float* ln1w = (const float*)d_in[1];
  const float* ln1b = (const float*)d_in[2];
  const float* ln2w = (const float*)d_in[3];
  const float* ln2b = (const float*)d_in[4];
  const float* wqkv = (const float*)d_in[5];
  const float* bqkv = (const float*)d_in[6];
  const float* wo   = (const float*)d_in[7];
  const float* bo   = (const float*)d_in[8];
  const float* wg   = (const float*)d_in[9];
  const float* w1   = (const float*)d_in[10];
  const float* w2   = (const float*)d_in[11];
  float* out = (float*)d_out;

  // workspace layout (float units), 135 MB = 33,750,000 floats:
  // [0,        4194304)   xres (f32)
  // [4194304,  20971520)  hmoe bf16 (16384x2048); earlier reused as:
  //                         qkv f32 [4194304,16777216), h1 f32 [16777216,20971520)
  // [20971520, 25165824)  h2 f32 (dead after gating) -> eo bf16 (16384x512)
  // [25165824, 27262976)  h2bf (8192x512 bf16)
  // [27262976, 29884416)  w1bf (5x512x2048 bf16)
  // [29884416, 32505856)  w2bf (5x2048x512 bf16)
  // [32505856, ...)       int buffers (~111K ints)
  if (ws_size < (size_t)135000000) return;
  float* ws   = (float*)d_ws;
  float* xres = ws;
  unsigned short* hmoe = (unsigned short*)(ws + 4194304);
  float* qkv  = ws + 4194304;
  float* h1   = ws + 16777216;
  float* h2   = ws + 20971520;
  unsigned short* eobf = (unsigned short*)(ws + 20971520);
  unsigned short* h2bf = (unsigned short*)(ws + 25165824);
  unsigned short* w1bf = (unsigned short*)(ws + 27262976);
  unsigned short* w2bf = (unsigned short*)(ws + 29884416);
  int* ibuf    = (int*)(ws + 32505856);
  int* e1      = ibuf;                 // 8192
  int* e2      = e1 + kT;              // 8192
  float* g1f   = (float*)(e2 + kT);    // 8192
  float* g2f   = g1f + kT;             // 8192
  int* keepr   = (int*)(g2f + kT);     // 8192
  int* slot1   = keepr + kT;           // 8192
  int* slot2   = slot1 + kT;           // 8192
  int* rowOf1  = slot2 + kT;           // 8192
  int* rowOf2  = rowOf1 + kT;          // 8192
  int* tot     = rowOf2 + kT;          // 2048*5
  int* gbase   = tot + kL * kNE;       // 2048*5
  int* tokOfRow= gbase + kL * kNE;     // 16384
  int* cnt     = tokOfRow + 2 * kT;    // 8
  int* ebase   = cnt + 8;              // 8

  // 0. weights -> bf16 (inputs only; do first)
  f2bf_kernel<<<5120, 256, 0, stream>>>(w1, w1bf, kNE * kE * kFF / 4);
  f2bf_kernel<<<5120, 256, 0, stream>>>(w2, w2bf, kNE * kFF * kE / 4);
  // 1. h1 = LN1(x)
  ln_kernel<<<kT, 256, 0, stream>>>(x, ln1w, ln1b, h1);
  // 2. qkv = h1 @ Wqkv^T + b  (M=8192, N=1536, K=512)
  gemm_kernel<1,0><<<dim3(12, 64, 1), 256, 0, stream>>>(
      h1, wqkv, bqkv, nullptr, qkv, kT, 1536, kE);
  // 3. attention (f32 flash), writes attn_out into h1
  flash_kernel<<<dim3(32, 32, 1), 256, 0, stream>>>(qkv, h1);
  // 4. x_res = x + attn_out @ Wo^T + bo  (M=8192, N=512, K=512)
  gemm_kernel<1,1><<<dim3(4, 64, 1), 256, 0, stream>>>(
      h1, wo, bo, x, xres, kT, kE, kE);
  // 5. h2 = LN2(x_res)
  ln_kernel<<<kT, 256, 0, stream>>>(xres, ln2w, ln2b, h2);
  // 6. gating per token (partitionable-XOR threefry — verified r8)
  gating_kernel<<<kL, 256, 0, stream>>>(h2, wg, e1, e2, g1f, g2f, keepr);
  // 6b. h2 -> bf16 (for MFMA FF1 A operand)
  f2bf_kernel<<<4096, 256, 0, stream>>>(h2, h2bf, kT * kE / 4);
  // 7. per-group plan (positions + capacity)
  plan_kernel<<<kL / 256, 256, 0, stream>>>(e1, e2, keepr, slot1, slot2, tot);
  // 8. per-expert scan; expert bases; token->row maps
  scan_kernel<<<kNE, 256, 0, stream>>>(tot, gbase, cnt);
  bases_kernel<<<1, 32, 0, stream>>>(cnt, ebase);
  rowmap_kernel<<<kT / 256, 256, 0, stream>>>(
      e1, e2, slot1, slot2, gbase, ebase, rowOf1, rowOf2, tokOfRow);
  // 9. hmoe = relu(gather(h2bf) @ w1bf[e])  -- bf16 MFMA
  moe_mfma_kernel<1,1,kE,kFF><<<dim3(16, 64, kNE), 256, 0, stream>>>(
      h2bf, w1bf, hmoe, tokOfRow, cnt, ebase);
  // 10. eo = hmoe @ w2bf[e]  -- bf16 MFMA
  moe_mfma_kernel<0,0,kFF,kE><<<dim3(4, 64, kNE), 256, 0, stream>>>(
      hmoe, w2bf, eobf, nullptr, cnt, ebase);
  // 11. out = x_res + g1*eo[r1] + g2*eo[r2]
  combine_kernel<<<kT, 128, 0, stream>>>(
      xres, eobf, g1f, g2f, rowOf1, rowOf2, out);
}